// Round 8
// baseline (121.153 us; speedup 1.0000x reference)
//
#include <hip/hip_runtime.h>
#include <math.h>

constexpr int Nn = 16384;
constexpr int ST = 68;                      // ws row stride (dwords): 64 qk + 4 pp
constexpr size_t NS = (size_t)Nn * 16;      // dwords per channel plane of npts

// ---- DPP helpers (pure VALU cross-lane, rows of 16) ----
template <int CTRL>
__device__ __forceinline__ float dpp_f(float x) {
    return __int_as_float(
        __builtin_amdgcn_update_dpp(0, __float_as_int(x), CTRL, 0xF, 0xF, false));
}
__device__ __forceinline__ float rsum16(float v) {
    v += dpp_f<0x128>(v); v += dpp_f<0x124>(v);
    v += dpp_f<0x122>(v); v += dpp_f<0x121>(v);
    return v;
}
__device__ __forceinline__ float rmax16(float v) {
    v = fmaxf(v, dpp_f<0x128>(v)); v = fmaxf(v, dpp_f<0x124>(v));
    v = fmaxf(v, dpp_f<0x122>(v)); v = fmaxf(v, dpp_f<0x121>(v));
    return v;
}

// ================= Kernel A: qk = Wk^T (q*scale), pp = Wp^T qk =================
// thread = (point, 16-channel quarter); no LDS. (unchanged from R7)
__global__ __launch_bounds__(256, 4) void qkpp_kernel(
    const float* __restrict__ points, const float* __restrict__ Wk,
    const float* __restrict__ Wp, float* __restrict__ ws)
{
    const int tid = threadIdx.x;
    const int lane = tid & 63;
    const int q = lane >> 4;                            // quarter 0..3
    const int pt = blockIdx.x * 64 + (tid >> 6) * 16 + (lane & 15);
    const int b = pt >> 14;
    const int n = pt & (Nn - 1);

    float qk[16];
#pragma unroll
    for (int k = 0; k < 16; ++k) qk[k] = 0.f;

    const float* prow = points + (size_t)b * 64 * Nn + n;
    const float* wkq = Wk + 16 * q;
#pragma unroll 4
    for (int c = 0; c < 64; ++c) {
        const float qv = prow[(size_t)c * Nn];          // coalesced (16n x4 dup -> 64B)
        const float4 w0 = *(const float4*)(wkq + c * 64 + 0);   // wave-broadcast (4 distinct)
        const float4 w1 = *(const float4*)(wkq + c * 64 + 4);
        const float4 w2 = *(const float4*)(wkq + c * 64 + 8);
        const float4 w3 = *(const float4*)(wkq + c * 64 + 12);
        qk[0]  = fmaf(qv, w0.x, qk[0]);  qk[1]  = fmaf(qv, w0.y, qk[1]);
        qk[2]  = fmaf(qv, w0.z, qk[2]);  qk[3]  = fmaf(qv, w0.w, qk[3]);
        qk[4]  = fmaf(qv, w1.x, qk[4]);  qk[5]  = fmaf(qv, w1.y, qk[5]);
        qk[6]  = fmaf(qv, w1.z, qk[6]);  qk[7]  = fmaf(qv, w1.w, qk[7]);
        qk[8]  = fmaf(qv, w2.x, qk[8]);  qk[9]  = fmaf(qv, w2.y, qk[9]);
        qk[10] = fmaf(qv, w2.z, qk[10]); qk[11] = fmaf(qv, w2.w, qk[11]);
        qk[12] = fmaf(qv, w3.x, qk[12]); qk[13] = fmaf(qv, w3.y, qk[13]);
        qk[14] = fmaf(qv, w3.z, qk[14]); qk[15] = fmaf(qv, w3.w, qk[15]);
    }
#pragma unroll
    for (int k = 0; k < 16; ++k) qk[k] *= 0.125f;       // fold SCALE

    // pp[j] = sum_c qk[c] * Wp[c][j]  (partial over own quarter, combine via shfl)
    float p0 = 0.f, p1 = 0.f, p2 = 0.f, p3 = 0.f;
#pragma unroll
    for (int k = 0; k < 16; ++k) {
        const float4 wp4 = *(const float4*)(Wp + (16 * q + k) * 4);
        p0 = fmaf(qk[k], wp4.x, p0);
        p1 = fmaf(qk[k], wp4.y, p1);
        p2 = fmaf(qk[k], wp4.z, p2);
        p3 = fmaf(qk[k], wp4.w, p3);
    }
    p0 += __shfl_xor(p0, 16); p0 += __shfl_xor(p0, 32);
    p1 += __shfl_xor(p1, 16); p1 += __shfl_xor(p1, 32);
    p2 += __shfl_xor(p2, 16); p2 += __shfl_xor(p2, 32);
    p3 += __shfl_xor(p3, 16); p3 += __shfl_xor(p3, 32);

    float* orow = ws + (size_t)pt * ST + 16 * q;
    ((float4*)orow)[0] = make_float4(qk[0],  qk[1],  qk[2],  qk[3]);
    ((float4*)orow)[1] = make_float4(qk[4],  qk[5],  qk[6],  qk[7]);
    ((float4*)orow)[2] = make_float4(qk[8],  qk[9],  qk[10], qk[11]);
    ((float4*)orow)[3] = make_float4(qk[12], qk[13], qk[14], qk[15]);
    if (q == 0)
        *(float4*)(ws + (size_t)pt * ST + 64) = make_float4(p0, p1, p2, p3);
}

// ====== Kernel B: logits + softmax + vbar + Wv matvec (channel-split pairs) ======
// Wave pair {2p, 2p+1} shares a 4-point group; wave 2p does channels 0-31,
// wave 2p+1 does 32-63 + pos + tail. npv[32]/wave -> ~60 VGPR -> 6 waves/SIMD.
__global__ __launch_bounds__(256, 6) void attn_out_kernel(
    const float* __restrict__ xyz, const float* __restrict__ nxyz,
    const float* __restrict__ npts, const float* __restrict__ Wv,
    const float* __restrict__ ws, float* __restrict__ out)
{
    __shared__ float wvT[67 * 68];              // [c][o], stride 68
    __shared__ float lexch[4][64];              // partial-logit exchange
    __shared__ float aexch[2][4][64];           // partial-out exchange [pair][j][lane]

    const int tid = threadIdx.x;
    for (int idx = tid; idx < 64 * 67; idx += 256) {
        const int o = idx / 67, c = idx - o * 67;
        wvT[c * 68 + o] = Wv[idx];
    }
    __syncthreads();

    const int w = tid >> 6;
    const int lane = tid & 63;
    const int s = lane & 15;
    const int nn = lane >> 4;
    const int pair = w >> 1;                    // 0,1
    const int half = w & 1;                     // 0: c 0-31; 1: c 32-63 (+pos/tail)
    const int gpt = blockIdx.x * 8 + pair * 4;  // 4-point group base
    const int b = gpt >> 14;
    const int ng = gpt & (Nn - 1);
    const int pt = gpt + nn;                    // this lane's point

    // ---- np half-stream: 32 coalesced dword loads (256B/instr) into regs ----
    const float* npb = npts + (size_t)(b * 64 + half * 32) * NS + (size_t)ng * 16 + lane;
    float npv[32];
#pragma unroll
    for (int c = 0; c < 32; ++c) npv[c] = npb[(size_t)c * NS];

    // ---- pos only in half==1 (no duplicated nxyz traffic) ----
    float d0 = 0.f, d1 = 0.f, d2 = 0.f, dn = 0.f;
    if (half) {
        const float nx0 = nxyz[((size_t)(b * 3 + 0) * Nn + ng) * 16 + lane];
        const float nx1 = nxyz[((size_t)(b * 3 + 1) * Nn + ng) * 16 + lane];
        const float nx2 = nxyz[((size_t)(b * 3 + 2) * Nn + ng) * 16 + lane];
        d0 = xyz[(size_t)(b * 3 + 0) * Nn + ng + nn] - nx0;
        d1 = xyz[(size_t)(b * 3 + 1) * Nn + ng + nn] - nx1;
        d2 = xyz[(size_t)(b * 3 + 2) * Nn + ng + nn] - nx2;
        dn = sqrtf(d0 * d0 + d1 * d1 + d2 * d2);
    }

    // ---- partial logit over own 32 channels (qk: 16B broadcast loads) ----
    const float* qrow = ws + (size_t)pt * ST + half * 32;
    float l0 = 0.f, l1 = 0.f, l2 = 0.f, l3 = 0.f;
#pragma unroll
    for (int jc = 0; jc < 8; ++jc) {
        const float4 qq = *(const float4*)(qrow + 4 * jc);
        l0 = fmaf(qq.x, npv[4 * jc + 0], l0);
        l1 = fmaf(qq.y, npv[4 * jc + 1], l1);
        l2 = fmaf(qq.z, npv[4 * jc + 2], l2);
        l3 = fmaf(qq.w, npv[4 * jc + 3], l3);
    }
    float lp = (l0 + l1) + (l2 + l3);
    if (half) {
        const float4 ppv = *(const float4*)(ws + (size_t)pt * ST + 64);
        lp += ppv.x * d0 + ppv.y * d1 + ppv.z * d2 + ppv.w * dn;
        // (bp term constant in s -> cancels in softmax)
    }

    // ---- combine partial logits across the pair ----
    lexch[w][lane] = lp;
    __syncthreads();
    const float logit = lp + lexch[w ^ 1][lane];

    // ---- softmax over s (pure DPP; duplicated in both waves of the pair) ----
    const float mx = rmax16(logit);
    const float e = __expf(logit - mx);
    const float se = rsum16(e);
    const float attn = e / se;

    // ---- fused vbar + Wv matvec over own 32 channels ----
    // rsum16 puts vbar[c] in ALL 16 lanes of row nn; lane (nn,s) owns o = 4s..4s+3.
    float a0 = 0.f, a1 = 0.f, a2 = 0.f, a3 = 0.f;
#pragma unroll
    for (int c = 0; c < 32; ++c) {
        const float r = rsum16(attn * npv[c]);                 // vbar[half*32+c, nn]
        const float4 wq = *(const float4*)&wvT[(half * 32 + c) * 68 + 4 * s];
        a0 = fmaf(r, wq.x, a0);
        a1 = fmaf(r, wq.y, a1);
        a2 = fmaf(r, wq.z, a2);
        a3 = fmaf(r, wq.w, a3);
    }
    if (half) {   // tail channels 64..66 (= tmp d0,d1,d2)
        const float t0 = rsum16(attn * d0);
        const float t1 = rsum16(attn * d1);
        const float t2 = rsum16(attn * d2);
        const float4 wA = *(const float4*)&wvT[64 * 68 + 4 * s];
        const float4 wB = *(const float4*)&wvT[65 * 68 + 4 * s];
        const float4 wC = *(const float4*)&wvT[66 * 68 + 4 * s];
        a0 = fmaf(t0, wA.x, a0); a1 = fmaf(t0, wA.y, a1);
        a2 = fmaf(t0, wA.z, a2); a3 = fmaf(t0, wA.w, a3);
        a0 = fmaf(t1, wB.x, a0); a1 = fmaf(t1, wB.y, a1);
        a2 = fmaf(t1, wB.z, a2); a3 = fmaf(t1, wB.w, a3);
        a0 = fmaf(t2, wC.x, a0); a1 = fmaf(t2, wC.y, a1);
        a2 = fmaf(t2, wC.z, a2); a3 = fmaf(t2, wC.w, a3);
        aexch[pair][0][lane] = a0;
        aexch[pair][1][lane] = a1;
        aexch[pair][2][lane] = a2;
        aexch[pair][3][lane] = a3;
    }
    __syncthreads();

    if (!half) {
        a0 += aexch[pair][0][lane];
        a1 += aexch[pair][1][lane];
        a2 += aexch[pair][2][lane];
        a3 += aexch[pair][3][lane];
        // out[o = 4s+j][ng+nn]; 16 x 16B segments per instr, sibling pairs +
        // adjacent blocks complete 64B lines in L2
        float* ob = out + ((size_t)(b * 64 + 4 * s) * Nn) + ng + nn;
        ob[0]              = a0;
        ob[(size_t)Nn]     = a1;
        ob[(size_t)Nn * 2] = a2;
        ob[(size_t)Nn * 3] = a3;
    }
}

extern "C" void kernel_launch(void* const* d_in, const int* in_sizes, int n_in,
                              void* d_out, int out_size, void* d_ws, size_t ws_size,
                              hipStream_t stream) {
    const float* xyz    = (const float*)d_in[0];
    const float* nxyz   = (const float*)d_in[1];
    const float* points = (const float*)d_in[2];
    const float* npts   = (const float*)d_in[3];
    const float* Wk     = (const float*)d_in[4];
    const float* Wv     = (const float*)d_in[5];
    const float* Wp     = (const float*)d_in[6];
    // d_in[7] = bp — unused: constant-in-s logit shift cancels in softmax
    float* out = (float*)d_out;
    float* ws = (float*)d_ws;   // [65536][68] fp32 = 17.8 MB, fully rewritten each call

    hipLaunchKernelGGL(qkpp_kernel,     dim3(1024), dim3(256), 0, stream,
                       points, Wk, Wp, ws);
    hipLaunchKernelGGL(attn_out_kernel, dim3(8192), dim3(256), 0, stream,
                       xyz, nxyz, npts, Wv, ws, out);
}